// Round 10
// baseline (1206.652 us; speedup 1.0000x reference)
//
#include <hip/hip_runtime.h>

#define DIM 1536
#define NH 12
#define HD 128
#define S_LEN 5400
#define SPAD 5440      // 85*64  (flash kv tiles / vt col stride)
#define MPAD 5504      // 43*128 (flash q tiles / GEMM2 M)
#define MPAD2 5632     // 22*256 (GEMM1 M, padded)
#define NQKV 4608
#define EPS_NORM 1e-6f

typedef __bf16 bf16_t;
typedef __bf16 bf16x8 __attribute__((ext_vector_type(8)));
typedef __bf16 bf16x4 __attribute__((ext_vector_type(4)));
typedef __bf16 bf16x2 __attribute__((ext_vector_type(2)));
typedef float  f32x4  __attribute__((ext_vector_type(4)));
typedef float  f32x16 __attribute__((ext_vector_type(16)));
typedef int    i32x2  __attribute__((ext_vector_type(2)));

// async global->LDS, 16B per lane; LDS dest is wave-uniform base + lane*16
#define GLOAD_LDS16(gp, lp) __builtin_amdgcn_global_load_lds( \
    (__attribute__((address_space(1))) void*)(void*)(gp),     \
    (__attribute__((address_space(3))) void*)(lp), 16, 0, 0)

// pack two f32 -> bf16x2 word (compiler emits cvt_pk)
__device__ __forceinline__ unsigned int pkbf(float a, float b) {
  union { bf16x2 h; unsigned int u; } c;
  c.h[0] = (__bf16)a; c.h[1] = (__bf16)b;
  return c.u;
}

// cross-half (lane ^ 32) reduce via permlane32_swap BUILTIN
__device__ __forceinline__ float xhalf_max(float x) {
  i32x2 r = __builtin_amdgcn_permlane32_swap(__float_as_int(x), __float_as_int(x),
                                             false, false);
  return fmaxf(__int_as_float(r.x), __int_as_float(r.y));
}
__device__ __forceinline__ float xhalf_sum(float x) {
  i32x2 r = __builtin_amdgcn_permlane32_swap(__float_as_int(x), __float_as_int(x),
                                             false, false);
  return __int_as_float(r.x) + __int_as_float(r.y);
}

// ---------------- merged conversion kernel (3-in-1) ----------------

#define CVT_NX 8448    // MPAD2*DIM/4/256
#define CVT_NW 6912    // NQKV*DIM/4/256
#define CVT_NO 2304    // DIM*DIM/4/256

__global__ __launch_bounds__(256) void cvt_all_kernel(
    const float* __restrict__ x, const float* __restrict__ qw,
    const float* __restrict__ kw, const float* __restrict__ vw,
    const float* __restrict__ ow, bf16_t* __restrict__ xb,
    bf16_t* __restrict__ wqkv, bf16_t* __restrict__ wob) {
  int b = blockIdx.x;
  if (b < CVT_NX) {
    size_t base = ((size_t)b * 256 + threadIdx.x) * 4;
    size_t row = base / DIM;
    float4 v = make_float4(0.f, 0.f, 0.f, 0.f);
    if (row < S_LEN) v = *(const float4*)&x[base];
    bf16x4 o; o[0] = (__bf16)v.x; o[1] = (__bf16)v.y; o[2] = (__bf16)v.z; o[3] = (__bf16)v.w;
    *(bf16x4*)&xb[base] = o;
  } else if (b < CVT_NX + CVT_NW) {
    size_t base = ((size_t)(b - CVT_NX) * 256 + threadIdx.x) * 4;
    int row = (int)(base / DIM);
    int col = (int)(base - (size_t)row * DIM);
    const float* src; int rr = row;
    if (rr >= 3072)      { src = vw; rr -= 3072; }
    else if (rr >= 1536) { src = kw; rr -= 1536; }
    else                 { src = qw; }
    float4 v = *(const float4*)&src[(size_t)rr * DIM + col];
    bf16x4 o; o[0] = (__bf16)v.x; o[1] = (__bf16)v.y; o[2] = (__bf16)v.z; o[3] = (__bf16)v.w;
    *(bf16x4*)&wqkv[base] = o;
  } else {
    size_t base = ((size_t)(b - CVT_NX - CVT_NW) * 256 + threadIdx.x) * 4;
    float4 v = *(const float4*)&ow[base];
    bf16x4 o; o[0] = (__bf16)v.x; o[1] = (__bf16)v.y; o[2] = (__bf16)v.z; o[3] = (__bf16)v.w;
    *(bf16x4*)&wob[base] = o;
  }
}

// ---------------- GEMM1: 256x256 tile, BK=64, 8 waves, 4-phase counted-vmcnt ----------------
// q,k blocks -> qkv[m][n]; v blocks (n0>=3072) -> fused transpose into vt.

__global__ __launch_bounds__(512, 2) void gemm1_256_kernel(
    const bf16_t* __restrict__ A, const bf16_t* __restrict__ B,
    bf16_t* __restrict__ C, bf16_t* __restrict__ vt,
    const float* __restrict__ bias0, const float* __restrict__ bias1,
    const float* __restrict__ bias2) {
  const int K = 1536, N = NQKV, KT = 24;
  __shared__ bf16_t lds[2][2][256 * 64];   // [buf][A/B][row*64 + pc*8] = 128 KB
  int tid = threadIdx.x;
  int lane = tid & 63, wave = tid >> 6, quad = lane >> 4, l16 = lane & 15;
  int wm2 = wave >> 2, wn4 = wave & 3;
  int m0 = blockIdx.y * 256, n0 = blockIdx.x * 256;
  const bf16_t* Ab = A + (size_t)m0 * K;
  const bf16_t* Bb = B + (size_t)n0 * K;
  f32x4 acc[8][4] = {};

  int srow = tid >> 3, spc = tid & 7;
  int ldst = srow * 64 + spc * 8;
  int sc8 = (spc ^ (srow & 7)) * 8;

#define G1_STAGE(buf, op, q, kt) \
  GLOAD_LDS16((op ? Bb : Ab) + (size_t)((q) * 64 + srow) * K + (kt) + sc8, \
              &lds[buf][op][(q) * 64 * 64 + ldst])

  G1_STAGE(0, 1, 0, 0); G1_STAGE(0, 1, 1, 0);
  G1_STAGE(0, 1, 2, 0); G1_STAGE(0, 1, 3, 0);
  G1_STAGE(0, 0, 0, 0); G1_STAGE(0, 0, 2, 0);
  G1_STAGE(0, 0, 1, 0); G1_STAGE(0, 0, 3, 0);

  int pcq0 = (0 * 4 + quad) ^ (l16 & 7);
  int pcq1 = (1 * 4 + quad) ^ (l16 & 7);

  for (int t = 0; t < KT; t++) {
    int cur = t & 1, nxt = cur ^ 1;
    int kn = (t + 1) * 64;
    bool st = (t + 1 < KT);

#define G1_PHASE(mh, nh2, STAGES, WAITS)                                      \
    {                                                                         \
      WAITS;                                                                  \
      __builtin_amdgcn_s_barrier();                                           \
      __builtin_amdgcn_sched_barrier(0);                                      \
      bf16x8 af[4][2], bfv[2][2];                                             \
      _Pragma("unroll")                                                       \
      for (int i2 = 0; i2 < 4; i2++) {                                        \
        int row = wm2 * 128 + ((mh) * 4 + i2) * 16 + l16;                     \
        af[i2][0] = *(const bf16x8*)&lds[cur][0][row * 64 + pcq0 * 8];        \
        af[i2][1] = *(const bf16x8*)&lds[cur][0][row * 64 + pcq1 * 8];        \
      }                                                                       \
      _Pragma("unroll")                                                       \
      for (int j2 = 0; j2 < 2; j2++) {                                        \
        int rowb = wn4 * 64 + ((nh2) * 2 + j2) * 16 + l16;                    \
        bfv[j2][0] = *(const bf16x8*)&lds[cur][1][rowb * 64 + pcq0 * 8];      \
        bfv[j2][1] = *(const bf16x8*)&lds[cur][1][rowb * 64 + pcq1 * 8];      \
      }                                                                       \
      if (st) { STAGES; }                                                     \
      asm volatile("s_waitcnt lgkmcnt(0)" ::: "memory");                      \
      __builtin_amdgcn_sched_barrier(0);                                      \
      __builtin_amdgcn_s_setprio(1);                                          \
      _Pragma("unroll")                                                       \
      for (int i2 = 0; i2 < 4; i2++)                                          \
        _Pragma("unroll")                                                     \
        for (int j2 = 0; j2 < 2; j2++)                                        \
          _Pragma("unroll")                                                   \
          for (int kk = 0; kk < 2; kk++)                                      \
            acc[(mh) * 4 + i2][(nh2) * 2 + j2] =                              \
                __builtin_amdgcn_mfma_f32_16x16x32_bf16(                      \
                    af[i2][kk], bfv[j2][kk],                                  \
                    acc[(mh) * 4 + i2][(nh2) * 2 + j2], 0, 0, 0);             \
      __builtin_amdgcn_s_setprio(0);                                          \
    }

    G1_PHASE(0, 0, G1_STAGE(nxt,1,0,kn); G1_STAGE(nxt,1,1,kn),
             if (st) asm volatile("s_waitcnt vmcnt(2)" ::: "memory");
             else    asm volatile("s_waitcnt vmcnt(0)" ::: "memory"));
    G1_PHASE(1, 0, G1_STAGE(nxt,1,2,kn); G1_STAGE(nxt,1,3,kn),
             if (st) asm volatile("s_waitcnt vmcnt(2)" ::: "memory");
             else    asm volatile("s_waitcnt vmcnt(0)" ::: "memory"));
    G1_PHASE(0, 1, G1_STAGE(nxt,0,0,kn); G1_STAGE(nxt,0,2,kn),
             asm volatile("s_waitcnt vmcnt(4)" ::: "memory"));
    G1_PHASE(1, 1, G1_STAGE(nxt,0,1,kn); G1_STAGE(nxt,0,3,kn),
             asm volatile("s_waitcnt vmcnt(6)" ::: "memory"));
#undef G1_PHASE
  }
#undef G1_STAGE

  bool isv = (n0 >= 3072);
#pragma unroll
  for (int j = 0; j < 4; j++) {
    int n = n0 + wn4 * 64 + j * 16 + l16;
    float bias = (n < 1536) ? bias0[n] : (n < 3072) ? bias1[n - 1536] : bias2[n - 3072];
    if (!isv) {
#pragma unroll
      for (int i = 0; i < 8; i++) {
#pragma unroll
        for (int r = 0; r < 4; r++) {
          int m = m0 + wm2 * 128 + i * 16 + quad * 4 + r;
          C[(size_t)m * N + n] = (__bf16)(acc[i][j][r] + bias);
        }
      }
    } else {
      int nd = n - 3072;
      bf16_t* vrow = vt + ((size_t)(nd >> 7) * HD + (nd & 127)) * SPAD;
#pragma unroll
      for (int i = 0; i < 8; i++) {
        int m = m0 + wm2 * 128 + i * 16 + quad * 4;
        if (m < SPAD) {
          bf16x4 vv;
#pragma unroll
          for (int r = 0; r < 4; r++) {
            float val = acc[i][j][r] + bias;
            vv[r] = (m + r < S_LEN) ? (__bf16)val : (__bf16)0.f;
          }
          *(bf16x4*)&vrow[m] = vv;
        }
      }
    }
  }
}

// ---------------- GEMM2 (128-tile, known-good): C = A @ B^T + bias ----------------

template<bool OUT_BF16>
__global__ __launch_bounds__(256) void gemm_bt_kernel(
    const bf16_t* __restrict__ A, const bf16_t* __restrict__ B, void* __restrict__ C,
    const float* __restrict__ bias0, const float* __restrict__ bias1,
    const float* __restrict__ bias2, int M, int N, int K, int Mvalid) {
  __shared__ bf16_t As[2][128 * 32];
  __shared__ bf16_t Bs[2][128 * 32];
  int tid = threadIdx.x;
  int lane = tid & 63, wave = tid >> 6, quad = lane >> 4, l16 = lane & 15;
  int m0 = blockIdx.y * 128, n0 = blockIdx.x * 128;
  int wm = (wave >> 1) * 64, wn = (wave & 1) * 64;
  const bf16_t* Ab = A + (size_t)m0 * K;
  const bf16_t* Bb = B + (size_t)n0 * K;
  f32x4 acc[4][4] = {};

  int eo0 = tid * 8;
  int row0 = eo0 >> 5, col0 = eo0 & 31;
  int eo1 = (256 + tid) * 8;
  int row1 = eo1 >> 5, col1 = eo1 & 31;

  GLOAD_LDS16(Ab + (size_t)row0 * K + col0, &As[0][eo0]);
  GLOAD_LDS16(Bb + (size_t)row0 * K + col0, &Bs[0][eo0]);
  GLOAD_LDS16(Ab + (size_t)row1 * K + col1, &As[0][eo1]);
  GLOAD_LDS16(Bb + (size_t)row1 * K + col1, &Bs[0][eo1]);
  asm volatile("s_waitcnt vmcnt(0)" ::: "memory");
  __builtin_amdgcn_s_barrier();
  __builtin_amdgcn_sched_barrier(0);

  int KT = K >> 5;
  for (int t = 0; t < KT; t++) {
    int cur = t & 1;
    if (t + 1 < KT) {
      int kn = (t + 1) << 5;
      GLOAD_LDS16(Ab + (size_t)row0 * K + kn + col0, &As[cur ^ 1][eo0]);
      GLOAD_LDS16(Bb + (size_t)row0 * K + kn + col0, &Bs[cur ^ 1][eo0]);
      GLOAD_LDS16(Ab + (size_t)row1 * K + kn + col1, &As[cur ^ 1][eo1]);
      GLOAD_LDS16(Bb + (size_t)row1 * K + kn + col1, &Bs[cur ^ 1][eo1]);
    }
    bf16x8 af[4], bfr[4];
#pragma unroll
    for (int i = 0; i < 4; i++)
      af[i] = *(const bf16x8*)&As[cur][(wm + i * 16 + l16) * 32 + quad * 8];
#pragma unroll
    for (int j = 0; j < 4; j++)
      bfr[j] = *(const bf16x8*)&Bs[cur][(wn + j * 16 + l16) * 32 + quad * 8];
#pragma unroll
    for (int i = 0; i < 4; i++)
#pragma unroll
      for (int j = 0; j < 4; j++)
        acc[i][j] = __builtin_amdgcn_mfma_f32_16x16x32_bf16(af[i], bfr[j], acc[i][j], 0, 0, 0);
    asm volatile("s_waitcnt vmcnt(0) lgkmcnt(0)" ::: "memory");
    __builtin_amdgcn_s_barrier();
    __builtin_amdgcn_sched_barrier(0);
  }
#pragma unroll
  for (int j = 0; j < 4; j++) {
    int n = n0 + wn + j * 16 + l16;
    float bias = (n < 1536) ? bias0[n] : (n < 3072) ? bias1[n - 1536] : bias2[n - 3072];
#pragma unroll
    for (int i = 0; i < 4; i++) {
#pragma unroll
      for (int r = 0; r < 4; r++) {
        int m = m0 + wm + i * 16 + quad * 4 + r;
        float v = acc[i][j][r] + bias;
        if (OUT_BF16) {
          ((bf16_t*)C)[(size_t)m * N + n] = (__bf16)v;
        } else {
          if (m < Mvalid) ((float*)C)[(size_t)m * N + n] = v;
        }
      }
    }
  }
}

// ---------------- RMSNorm + RoPE for q,k ----------------

__global__ __launch_bounds__(256) void rope_qk_kernel(
    const bf16_t* __restrict__ qkv, const float* __restrict__ nqw,
    const float* __restrict__ nkw, const float* __restrict__ fcos,
    const float* __restrict__ fsin, bf16_t* __restrict__ qout,
    bf16_t* __restrict__ kout) {
  int s = blockIdx.x;              // 0..MPAD-1
  int tid = threadIdx.x;
  bool valid = s < S_LEN;
  int f = s / 900, hh = (s / 30) % 30, ww = s % 30;
  __shared__ float red[4];
  for (int which = 0; which < 2; which++) {
    const bf16_t* src = qkv + (size_t)s * NQKV + which * DIM;
    const float* nw = which ? nkw : nqw;
    bf16_t* dst = (which ? kout : qout) + (size_t)s * DIM;
    // 0.12751742686 = (1/sqrt(128)) * log2(e)
    float osc = which ? 1.0f : 0.12751742686f;
    float v[6]; float ss = 0.f;
#pragma unroll
    for (int i = 0; i < 6; i++) {
      v[i] = valid ? (float)src[tid * 6 + i] : 0.f;
      ss += v[i] * v[i];
    }
#pragma unroll
    for (int off = 32; off >= 1; off >>= 1) ss += __shfl_down(ss, off);
    if ((tid & 63) == 0) red[tid >> 6] = ss;
    __syncthreads();
    float tot = red[0] + red[1] + red[2] + red[3];
    float rn = rsqrtf(tot * (1.f / DIM) + EPS_NORM);
    __syncthreads();
#pragma unroll
    for (int i = 0; i < 3; i++) {
      int e0 = tid * 6 + 2 * i;
      int p = e0 >> 1;
      int cc = p & 63;
      int pos = (cc < 22) ? f : (cc < 43) ? hh : ww;  // split [22,21,21]
      float c = fcos[pos * 64 + cc], sn = fsin[pos * 64 + cc];
      float xr = v[2 * i] * rn * nw[e0];
      float xi = v[2 * i + 1] * rn * nw[e0 + 1];
      dst[e0]     = (__bf16)((xr * c - xi * sn) * osc);
      dst[e0 + 1] = (__bf16)((xr * sn + xi * c) * osc);
    }
  }
}

// ---------------- flash attention: TWO-KV-STREAM 8-wave blocks ----------------
// Rationale (R1-R9): flash insensitive to staging depth/KVBLK/tail/conflicts;
// binding constraint = 2 waves/SIMD cannot overlap per-wave serial chains.
// This doubles waves/SIMD to 4 with ZERO new fragment layouts and SAME
// staging traffic: 512 threads = 4 q-groups x 2 kv-streams; stream st
// processes tiles 2r+st using buffer st (each tile staged ONCE per block);
// per-stream online softmax; one log2-domain (m,l,O) merge at the end
// (R4-harness-proven combine math). Odd tile count: stream1's last round
// is a fully-masked tile (P=0), V source clamped in-bounds.
// Per-wave compute body is R3-exact (best measured 332 us).

__global__ __launch_bounds__(512, 4) void flash_attn_kernel(
    const bf16_t* __restrict__ q, const bf16_t* __restrict__ k,
    const bf16_t* __restrict__ vt, bf16_t* __restrict__ o) {
  __shared__ bf16_t Ks[2][64 * 128];   // [stream][kv 64][k 128], chunk c at pc=c^(row&15)
  __shared__ bf16_t Vs[2][64 * 128];   // [stream] d-pair rows, chunk cp=(d&1)*8+(kv>>3), pc=cp^(r&15)
  __shared__ float ml1[4][2][32];      // stream1 (m,l) per q-group
  int head = blockIdx.y;
  int s0 = blockIdx.x * 128;
  int tid = threadIdx.x, w = tid >> 6, lane = tid & 63;
  int g = w & 3, st = w >> 2;          // q-group, kv-stream
  int l31 = lane & 31, hh = lane >> 5;

  bf16x8 bq[8];
  {
    const bf16_t* qp = &q[(size_t)(s0 + g * 32 + l31) * DIM + head * HD + hh * 8];
#pragma unroll
    for (int kc = 0; kc < 8; kc++) bq[kc] = *(const bf16x8*)(qp + kc * 16);
  }

  float m_i = -1e30f, l_i = 0.f;
  f32x16 oacc[4] = {};   // O^T: d = dt*32 + (r&3)+8*(r>>2)+4*hh, col q = l31

  const int NR = 43;     // rounds; tiles 2r (stream0) and 2r+1 (stream1); 85 real

  for (int r = 0; r < NR; r++) {
    // ---- stage both streams' tiles (once per block per tile)
#pragma unroll
    for (int it = 0; it < 4; it++) {
      int slot = it * 512 + tid;
      int b = slot >> 10, sI = slot & 1023;
      int row = sI >> 4, pc = sI & 15;
      int c = pc ^ (row & 15);
      int ktb = (2 * r + b) * 64;     // K rows <= 5503 < MPAD: in-bounds
      GLOAD_LDS16(k + (size_t)(ktb + row) * DIM + head * HD + c * 8, &Ks[b][sI * 8]);
    }
#pragma unroll
    for (int it = 0; it < 4; it++) {
      int slot = it * 512 + tid;
      int b = slot >> 10, sI = slot & 1023;
      int row = sI >> 4, pc = sI & 15;
      int cp = pc ^ (row & 15);
      int d = 2 * row + (cp >> 3);
      int ktv = (2 * r + b) * 64;
      if (ktv > SPAD - 64) ktv = SPAD - 64;   // clamp (tile 85: masked anyway)
      GLOAD_LDS16(vt + ((size_t)head * HD + d) * SPAD + ktv + (cp & 7) * 8, &Vs[b][sI * 8]);
    }
    asm volatile("s_waitcnt vmcnt(0)" ::: "memory");
    __builtin_amdgcn_s_barrier();
    __builtin_amdgcn_sched_barrier(0);

    int kt = (2 * r + st) * 64;

    // ---- S^T = K Q^T : 2 kv-subtiles x 8 k-chunks of 32x32x16
    f32x16 sacc[2] = {};
    __builtin_amdgcn_s_setprio(1);
#pragma unroll
    for (int ns = 0; ns < 2; ns++) {
      int row = ns * 32 + l31;
#pragma unroll
      for (int kc = 0; kc < 8; kc++) {
        int pc = (kc * 2 + hh) ^ (row & 15);
        bf16x8 ak = *(const bf16x8*)&Ks[st][row * 128 + pc * 8];
        sacc[ns] = __builtin_amdgcn_mfma_f32_32x32x16_bf16(ak, bq[kc], sacc[ns], 0, 0, 0);
      }
    }
    __builtin_amdgcn_s_setprio(0);

    // ---- mask (final tiles)
    if (kt + 64 > S_LEN) {
#pragma unroll
      for (int ns = 0; ns < 2; ns++)
#pragma unroll
        for (int r2 = 0; r2 < 16; r2++) {
          int kvg = kt + ns * 32 + (r2 & 3) + 8 * (r2 >> 2) + 4 * hh;
          if (kvg >= S_LEN) sacc[ns][r2] = -1e30f;
        }
    }

    // ---- online softmax (log2 domain), tree max, permlane cross-half
    float mx;
    {
      float tm[8];
#pragma unroll
      for (int i = 0; i < 8; i++)
        tm[i] = fmaxf(fmaxf(sacc[0][i], sacc[0][i + 8]),
                      fmaxf(sacc[1][i], sacc[1][i + 8]));
#pragma unroll
      for (int i = 0; i < 4; i++) tm[i] = fmaxf(tm[i], tm[i + 4]);
      mx = fmaxf(fmaxf(tm[0], tm[2]), fmaxf(tm[1], tm[3]));
    }
    mx = xhalf_max(mx);
    if (!__all(mx - m_i <= 11.5f)) {   // 11.5 ~= 8*log2(e)
      float mn = fmaxf(m_i, mx);
      float al = __builtin_amdgcn_exp2f(m_i - mn);
      l_i *= al;
#pragma unroll
      for (int dt = 0; dt < 4; dt++)
#pragma unroll
        for (int r2 = 0; r2 < 16; r2++) oacc[dt][r2] *= al;
      m_i = mn;
    }
#pragma unroll
    for (int ns = 0; ns < 2; ns++)
#pragma unroll
      for (int r2 = 0; r2 < 16; r2++)
        sacc[ns][r2] = __builtin_amdgcn_exp2f(sacc[ns][r2] - m_i);
    float rs;
    {
      float ts[8];
#pragma unroll
      for (int i = 0; i < 8; i++)
        ts[i] = (sacc[0][i] + sacc[0][i + 8]) + (sacc[1][i] + sacc[1][i + 8]);
#pragma unroll
      for (int i = 0; i < 4; i++) ts[i] += ts[i + 4];
      rs = (ts[0] + ts[2]) + (ts[1] + ts[3]);
    }
    l_i += xhalf_sum(rs);

    // ---- O^T += V^T P^T : in-register P (T12), 4 kv-chunks of 32x32x16
    __builtin_amdgcn_s_setprio(1);
#pragma unroll
    for (int kvc = 0; kvc < 4; kvc++) {
      int ns = kvc >> 1, rb = (kvc & 1) * 8;
      int w0 = (int)pkbf(sacc[ns][rb + 0], sacc[ns][rb + 1]);
      int w1 = (int)pkbf(sacc[ns][rb + 2], sacc[ns][rb + 3]);
      int w2 = (int)pkbf(sacc[ns][rb + 4], sacc[ns][rb + 5]);
      int w3 = (int)pkbf(sacc[ns][rb + 6], sacc[ns][rb + 7]);
      i32x2 r02 = __builtin_amdgcn_permlane32_swap(w0, w2, false, false);
      i32x2 r13 = __builtin_amdgcn_permlane32_swap(w1, w3, false, false);
      union { unsigned int u[4]; bf16x8 v8; } bpu;
      bpu.u[0] = (unsigned int)r02.x; bpu.u[1] = (unsigned int)r13.x;
      bpu.u[2] = (unsigned int)r02.y; bpu.u[3] = (unsigned int)r13.y;
      bf16x8 bp = bpu.v8;
#pragma unroll
      for (int dt = 0; dt < 4; dt++) {
        int d = dt * 32 + l31;
        int rr2 = d >> 1;
        int cp = ((d & 1) << 3) | (kvc * 2 + hh);
        int pc = cp ^ (rr2 & 15);
        bf16x8 av = *(const bf16x8*)&Vs[st][rr2 * 128 + pc * 8];
        oacc[dt] = __builtin_amdgcn_mfma_f32_32x32x16_bf16(av, bp, oacc[dt], 0, 0, 0);
      }
    }
    __builtin_amdgcn_s_setprio(0);

    // ---- all waves done reading before next round's staging overwrites
    asm volatile("s_waitcnt lgkmcnt(0)" ::: "memory");
    __builtin_amdgcn_s_barrier();
    __builtin_amdgcn_sched_barrier(0);
  }

  // ---- cross-stream merge: stream1 -> LDS; stream0 combines (log2 domain)
  float* Og = (float*)((g < 2 ? (char*)Ks : (char*)Vs) + (g & 1) * 16384);
  if (st == 1) {
#pragma unroll
    for (int dt = 0; dt < 4; dt++)
#pragma unroll
      for (int q4 = 0; q4 < 4; q4++) {
        f32x4 vv;
#pragma unroll
        for (int r4 = 0; r4 < 4; r4++) vv[r4] = oacc[dt][q4 * 4 + r4];
        *(f32x4*)&Og[((dt * 4 + q4) * 64 + lane) * 4] = vv;
      }
    if (hh == 0) { ml1[g][0][l31] = m_i; ml1[g][1][l31] = l_i; }
  }
  __syncthreads();
  if (st == 1) return;

  {
    float m1v = ml1[g][0][l31], l1v = ml1[g][1][l31];
    float mm = fmaxf(m_i, m1v);
    float a0 = __builtin_amdgcn_exp2f(m_i - mm);
    float a1 = __builtin_amdgcn_exp2f(m1v - mm);
    l_i = l_i * a0 + l1v * a1;
#pragma unroll
    for (int dt = 0; dt < 4; dt++)
#pragma unroll
      for (int q4 = 0; q4 < 4; q4++) {
        f32x4 vv = *(const f32x4*)&Og[((dt * 4 + q4) * 64 + lane) * 4];
#pragma unroll
        for (int r4 = 0; r4 < 4; r4++)
          oacc[dt][q4 * 4 + r4] = oacc[dt][q4 * 4 + r4] * a0 + vv[r4] * a1;
      }
  }

  // ---- epilogue: O^T -> per-group LDS transpose -> global (stream0 waves)
  bf16_t* scr = (bf16_t*)Og;   // same-wave DS ordering: reads above retire first
  float inv = 1.f / l_i;
  int qr = lane >> 1, seg = lane & 1;
  int srow = s0 + g * 32 + qr;
#pragma unroll
  for (int half = 0; half < 2; half++) {
#pragma unroll
    for (int dl = 0; dl < 2; dl++) {
      int dt = half * 2 + dl;
#pragma unroll
      for (int tt = 0; tt < 4; tt++) {
        bf16x4 v;
#pragma unroll
        for (int r4 = 0; r4 < 4; r4++) v[r4] = (__bf16)(oacc[dt][tt * 4 + r4] * inv);
        int c8 = dl * 8 + 2 * tt + hh;
        int pc8 = c8 ^ (l31 & 15);
        *(bf16x4*)&scr[l31 * 64 + pc8 * 4] = v;
      }
    }
#pragma unroll
    for (int i = 0; i < 4; i++) {
      int c8 = seg * 8 + 2 * i;
      bf16x4 lo = *(const bf16x4*)&scr[qr * 64 + ((c8) ^ (qr & 15)) * 4];
      bf16x4 hi = *(const bf16x4*)&scr[qr * 64 + ((c8 + 1) ^ (qr & 15)) * 4];
      bf16x8 val;
#pragma unroll
      for (int j = 0; j < 4; j++) { val[j] = lo[j]; val[j + 4] = hi[j]; }
      if (srow < S_LEN)
        *(bf16x8*)&o[(size_t)srow * DIM + head * HD + half * 64 + seg * 32 + i * 8] = val;
    }
  }
}

// ---------------- launch ----------------

extern "C" void kernel_launch(void* const* d_in, const int* in_sizes, int n_in,
                              void* d_out, int out_size, void* d_ws, size_t ws_size,
                              hipStream_t stream) {
  const float* x    = (const float*)d_in[0];
  const float* q_w  = (const float*)d_in[1];
  const float* q_b  = (const float*)d_in[2];
  const float* k_w  = (const float*)d_in[3];
  const float* k_b  = (const float*)d_in[4];
  const float* v_w  = (const float*)d_in[5];
  const float* v_b  = (const float*)d_in[6];
  const float* o_w  = (const float*)d_in[7];
  const float* o_b  = (const float*)d_in[8];
  const float* nqw  = (const float*)d_in[9];
  const float* nkw  = (const float*)d_in[10];
  const float* fcos = (const float*)d_in[11];
  const float* fsin = (const float*)d_in[12];

  char* ws = (char*)d_ws;
  bf16_t* xb   = (bf16_t*)(ws + 0);           // 17,301,504
  bf16_t* wqkv = (bf16_t*)(ws + 17301504);    // 14,155,776
  bf16_t* wob  = (bf16_t*)(ws + 31457280);    //  4,718,592
  bf16_t* qkv  = (bf16_t*)(ws + 36175872);    // 51,904,512
  bf16_t* qb   = (bf16_t*)(ws + 88080384);    // 16,908,288
  bf16_t* kb   = (bf16_t*)(ws + 104988672);   // 16,908,288
  bf16_t* vtb  = (bf16_t*)(ws + 121896960);   // 16,711,680 (own region)
  bf16_t* aob  = (bf16_t*)(ws + 36175872);    // alias qkv (q,k parts dead after rope)

  cvt_all_kernel<<<CVT_NX + CVT_NW + CVT_NO, 256, 0, stream>>>(
      x, q_w, k_w, v_w, o_w, xb, wqkv, wob);

  gemm1_256_kernel<<<dim3(NQKV / 256, MPAD2 / 256), 512, 0, stream>>>(
      xb, wqkv, qkv, vtb, q_b, k_b, v_b);

  rope_qk_kernel<<<MPAD, 256, 0, stream>>>(qkv, nqw, nkw, fcos, fsin, qb, kb);

  flash_attn_kernel<<<dim3(MPAD / 128, NH), 512, 0, stream>>>(qb, kb, vtb, aob);

  gemm_bt_kernel<false><<<dim3(DIM / 128, MPAD / 128), 256, 0, stream>>>(
      aob, wob, d_out, o_b, o_b, o_b, MPAD, DIM, DIM, S_LEN);
}